// Round 1
// baseline (311.957 us; speedup 1.0000x reference)
//
#include <hip/hip_runtime.h>
#include <hip/hip_bf16.h>

#define BB 8
#define TT 256
#define DIN 64
#define DD 128

__device__ __forceinline__ float gelu_tanh(float x) {
  float x3 = x * x * x;
  return 0.5f * x * (1.0f + tanhf(0.7978845608028654f * (x + 0.044715f * x3)));
}
__device__ __forceinline__ float sigmoidf(float x) {
  return 1.0f / (1.0f + __expf(-x));
}

template <typename T> __device__ __forceinline__ float getv(const void* p, int i);
template <> __device__ __forceinline__ float getv<float>(const void* p, int i) {
  return ((const float*)p)[i];
}
template <> __device__ __forceinline__ float getv<__hip_bfloat16>(const void* p, int i) {
  return __bfloat162float(((const __hip_bfloat16*)p)[i]);
}

// DPP-based add from a statically-controlled source lane. VALU latency
// (~8 cyc/stage) instead of ds_swizzle's DS-pipe (~120 cyc/stage).
template <int CTRL>
__device__ __forceinline__ float dpp_add(float x) {
  int s = __builtin_amdgcn_update_dpp(0, __float_as_int(x), CTRL, 0xF, 0xF, true);
  return x + __int_as_float(s);
}

// Sum across a 16-lane row (chains are 16 consecutive lanes, row-aligned).
// quad_perm xor1, quad_perm xor2 -> each lane holds its quad-sum;
// row_ror:4 + row_ror:8 -> every lane holds the sum of all 4 quads.
__device__ __forceinline__ float rowsum16(float p) {
  p = dpp_add<0xB1>(p);   // quad_perm [1,0,3,2]  (xor 1)
  p = dpp_add<0x4E>(p);   // quad_perm [2,3,0,1]  (xor 2)
  p = dpp_add<0x124>(p);  // row_ror:4
  p = dpp_add<0x128>(p);  // row_ror:8
  return p;
}

// ---------------------------------------------------------------------------
// k0: dtype detector. Interprets x's first 2048 uint16 as bf16; real bf16
// N(0,1) data decodes ~99.9% into [1e-4,100]; an fp32 bitstream only ~55%.
// flag=1 -> bf16, flag=0 -> fp32.
// ---------------------------------------------------------------------------
__global__ void k0_detect(const void* x, int* flag) {
  __shared__ int cnt;
  if (threadIdx.x == 0) cnt = 0;
  __syncthreads();
  const unsigned short* u = (const unsigned short*)x;
  int good = 0;
  for (int idx = threadIdx.x; idx < 2048; idx += 256) {
    unsigned int bits = ((unsigned int)u[idx]) << 16;
    float f = __uint_as_float(bits);
    float a = fabsf(f);
    if (a == 0.0f || (a > 1e-4f && a < 100.0f)) good++;
  }
  atomicAdd(&cnt, good);
  __syncthreads();
  if (threadIdx.x == 0) *flag = (cnt >= 1536) ? 1 : 0;
}

// ---------------------------------------------------------------------------
// k1: per (b,t) row: f = gelu(x@W_b+b_b); k=f@Wk; v=f@Wv; meta scalars.
// q and f kept only for t=T-1 (only fused[:, -1, :] feeds the head).
// Grid 2048 blocks x 128 threads.
// ---------------------------------------------------------------------------
template <typename T>
__device__ void k1_body(const void* x, const void* W_b, const void* b_b,
                        const void* Wk, const void* Wv, const void* Wq,
                        const void* W_m, const void* b_m,
                        float* kout, float* vout, float* scal4,
                        float* q_last, float* f_last) {
  const int row = blockIdx.x;          // 0..2047
  const int b = row >> 8, t = row & 255;
  const int tid = threadIdx.x;         // 0..127
  __shared__ float xs[DIN];
  __shared__ float fs[DD];
  if (tid < DIN) xs[tid] = getv<T>(x, row * DIN + tid);
  __syncthreads();

  float acc = getv<T>(b_b, tid);
#pragma unroll 8
  for (int d = 0; d < DIN; ++d) acc += xs[d] * getv<T>(W_b, d * DD + tid);
  float f = gelu_tanh(acc);
  fs[tid] = f;
  __syncthreads();

  float ak = 0.0f, av = 0.0f;
#pragma unroll 8
  for (int c = 0; c < DD; ++c) {
    float fc = fs[c];
    ak += fc * getv<T>(Wk, c * DD + tid);
    av += fc * getv<T>(Wv, c * DD + tid);
  }
  kout[row * DD + tid] = ak;
  vout[row * DD + tid] = av;

  if (t == TT - 1) {
    float aq = 0.0f;
#pragma unroll 8
    for (int c = 0; c < DD; ++c) aq += fs[c] * getv<T>(Wq, c * DD + tid);
    q_last[b * DD + tid] = aq;
    f_last[b * DD + tid] = f;
  }
  if (tid < 4) {
    float val = 0.0f;
    if (tid < 3) {
      float a = getv<T>(b_m, tid);
      for (int c = 0; c < DD; ++c) a += fs[c] * getv<T>(W_m, c * 3 + tid);
      float s = sigmoidf(a);
      val = (tid == 0) ? 0.01f * s : ((tid == 1) ? s : 0.1f * s);
    }
    scal4[row * 4 + tid] = val;  // (theta, eta, alpha, 0)
  }
}

__global__ __launch_bounds__(128) void k1_kern(
    const void* x, const void* W_b, const void* b_b, const void* Wk,
    const void* Wv, const void* Wq, const void* W_m, const void* b_m,
    const int* flag, float* kout, float* vout, float* scal4, float* q_last,
    float* f_last) {
  if (*flag)
    k1_body<__hip_bfloat16>(x, W_b, b_b, Wk, Wv, Wq, W_m, b_m, kout, vout,
                            scal4, q_last, f_last);
  else
    k1_body<float>(x, W_b, b_b, Wk, Wv, Wq, W_m, b_m, kout, vout, scal4,
                   q_last, f_last);
}

// ---------------------------------------------------------------------------
// k2: the scan. 1024 independent row-chains (b,i); one chain = 16 lanes,
// 8 fp32 M + 8 fp32 S elems per lane in registers. 64 blocks x 256 threads.
//
// Latency-chain optimizations vs prior version:
//  - b = blockIdx&7: all 8 blocks streaming the same kbuf[b] land on the
//    same XCD (round-robin dispatch), sharing its L2 (k+v slice = 256KB).
//  - 4-deep explicit software pipeline (static register slots) so load
//    latency (L2 ~220cyc) hides under 4 steps of compute.
//  - cross-lane reduction via DPP (quad_perm/row_ror), all-VALU, instead of
//    4 serial ds_swizzle (~120cyc each) through the DS pipe.
// ---------------------------------------------------------------------------
__global__ __launch_bounds__(256) void k2_scan(
    const float* __restrict__ kbuf, const float* __restrict__ vbuf,
    const float* __restrict__ scal, const float* __restrict__ q_last,
    float* __restrict__ m_last) {
  const int tid = threadIdx.x;
  const int g = tid & 15;
  const int cidx = tid >> 4;
  const int b = blockIdx.x & 7;                    // XCD id = blockIdx % 8
  const int i = ((blockIdx.x >> 3) << 4) + cidx;   // i-group from high bits

  const float4* kp = (const float4*)(kbuf + (size_t)b * TT * DD) + (g << 1);
  const float* vp = vbuf + (size_t)b * TT * DD + i;
  const float4* sp = (const float4*)(scal) + b * TT;

  float4 Ma = {0, 0, 0, 0}, Mb = {0, 0, 0, 0};
  float4 Sa = {0, 0, 0, 0}, Sb = {0, 0, 0, 0};

  // 4-deep pipeline: explicit named slots (compile-time indexing only).
  float4 ka0 = kp[0 * 32], kb0 = kp[0 * 32 + 1], sc0 = sp[0];
  float4 ka1 = kp[1 * 32], kb1 = kp[1 * 32 + 1], sc1 = sp[1];
  float4 ka2 = kp[2 * 32], kb2 = kp[2 * 32 + 1], sc2 = sp[2];
  float4 ka3 = kp[3 * 32], kb3 = kp[3 * 32 + 1], sc3 = sp[3];
  float v0 = vp[0 * 128], v1 = vp[1 * 128], v2 = vp[2 * 128], v3 = vp[3 * 128];

#define K2_STEP(KA, KB, VV, SC)                                              \
  {                                                                          \
    float p = (Ma.x * KA.x + Ma.y * KA.y) + (Ma.z * KA.z + Ma.w * KA.w) +    \
              (Mb.x * KB.x + Mb.y * KB.y) + (Mb.z * KB.z + Mb.w * KB.w);     \
    p = rowsum16(p);                                                         \
    const float err = p - VV;                                                \
    const float c = SC.x * err;   /* theta * err */                          \
    const float et = SC.y;        /* eta */                                  \
    const float am = 1.0f - SC.z; /* 1 - alpha */                            \
    Sa.x = et * Sa.x - c * KA.x;  Ma.x = am * Ma.x + Sa.x;                   \
    Sa.y = et * Sa.y - c * KA.y;  Ma.y = am * Ma.y + Sa.y;                   \
    Sa.z = et * Sa.z - c * KA.z;  Ma.z = am * Ma.z + Sa.z;                   \
    Sa.w = et * Sa.w - c * KA.w;  Ma.w = am * Ma.w + Sa.w;                   \
    Sb.x = et * Sb.x - c * KB.x;  Mb.x = am * Mb.x + Sb.x;                   \
    Sb.y = et * Sb.y - c * KB.y;  Mb.y = am * Mb.y + Sb.y;                   \
    Sb.z = et * Sb.z - c * KB.z;  Mb.z = am * Mb.z + Sb.z;                   \
    Sb.w = et * Sb.w - c * KB.w;  Mb.w = am * Mb.w + Sb.w;                   \
  }

#define K2_REFILL(SLOT_KA, SLOT_KB, SLOT_V, SLOT_SC, TN)                     \
  {                                                                          \
    const int tn = (TN) & (TT - 1); /* wraps at end; values unused */        \
    SLOT_KA = kp[tn * 32];                                                   \
    SLOT_KB = kp[tn * 32 + 1];                                               \
    SLOT_V = vp[tn * 128];                                                   \
    SLOT_SC = sp[tn];                                                        \
  }

  for (int t = 0; t < TT; t += 4) {
    K2_STEP(ka0, kb0, v0, sc0);
    K2_REFILL(ka0, kb0, v0, sc0, t + 4);
    K2_STEP(ka1, kb1, v1, sc1);
    K2_REFILL(ka1, kb1, v1, sc1, t + 5);
    K2_STEP(ka2, kb2, v2, sc2);
    K2_REFILL(ka2, kb2, v2, sc2, t + 6);
    K2_STEP(ka3, kb3, v3, sc3);
    K2_REFILL(ka3, kb3, v3, sc3, t + 7);
  }
#undef K2_STEP
#undef K2_REFILL

  const float4* qp = (const float4*)(q_last + b * DD) + (g << 1);
  float4 qa = qp[0], qb = qp[1];
  float p = (Ma.x * qa.x + Ma.y * qa.y) + (Ma.z * qa.z + Ma.w * qa.w) +
            (Mb.x * qb.x + Mb.y * qb.y) + (Mb.z * qb.z + Mb.w * qb.w);
  p = rowsum16(p);
  if (g == 0) m_last[b * DD + i] = p;
}

// ---------------------------------------------------------------------------
// k3: head. gate -> fused -> W1+LN+gelu -> W2. 8 blocks x 256 threads.
// ---------------------------------------------------------------------------
template <typename T>
__device__ void k3_body(const float* f_last, const float* m_last,
                        const void* W_f, const void* b_f, const void* W1,
                        const void* b1, const void* g1, const void* be1,
                        const void* W2, const void* b2, void* out) {
  const int b = blockIdx.x, tid = threadIdx.x;
  __shared__ float fm[2 * DD];
  __shared__ float fused[DD];
  __shared__ float tmp[DD];
  __shared__ float h[DD];
  __shared__ float smu, srs;

  fm[tid] = (tid < DD) ? f_last[b * DD + tid] : m_last[b * DD + tid - DD];
  __syncthreads();

  if (tid < DD) {
    float a = getv<T>(b_f, tid);
#pragma unroll 8
    for (int c = 0; c < 2 * DD; ++c) a += fm[c] * getv<T>(W_f, c * DD + tid);
    float gte = sigmoidf(a);
    fused[tid] = fm[tid] * gte + fm[DD + tid] * (1.0f - gte);
  }
  __syncthreads();

  if (tid < DD) {
    float a = getv<T>(b1, tid);
#pragma unroll 8
    for (int c = 0; c < DD; ++c) a += fused[c] * getv<T>(W1, c * DD + tid);
    tmp[tid] = a;
  }
  __syncthreads();

  if (tid == 0) {
    float s = 0.0f;
    for (int c = 0; c < DD; ++c) s += tmp[c];
    float mu = s / (float)DD;
    float s2 = 0.0f;
    for (int c = 0; c < DD; ++c) {
      float d = tmp[c] - mu;
      s2 += d * d;
    }
    smu = mu;
    srs = rsqrtf(s2 / (float)DD + 1e-5f);
  }
  __syncthreads();

  if (tid < DD)
    h[tid] = gelu_tanh((tmp[tid] - smu) * srs * getv<T>(g1, tid) +
                       getv<T>(be1, tid));
  __syncthreads();

  for (int j = tid; j < 672; j += 256) {
    float a = getv<T>(b2, j);
#pragma unroll 8
    for (int c = 0; c < DD; ++c) a += h[c] * getv<T>(W2, c * 672 + j);
    if (sizeof(T) == 2)
      ((__hip_bfloat16*)out)[b * 672 + j] = __float2bfloat16(a);
    else
      ((float*)out)[b * 672 + j] = a;
  }
}

__global__ __launch_bounds__(256) void k3_kern(
    const float* f_last, const float* m_last, const void* W_f,
    const void* b_f, const void* W1, const void* b1, const void* g1,
    const void* be1, const void* W2, const void* b2, const int* flag,
    void* out) {
  if (*flag)
    k3_body<__hip_bfloat16>(f_last, m_last, W_f, b_f, W1, b1, g1, be1, W2, b2,
                            out);
  else
    k3_body<float>(f_last, m_last, W_f, b_f, W1, b1, g1, be1, W2, b2, out);
}

// ---------------------------------------------------------------------------
extern "C" void kernel_launch(void* const* d_in, const int* in_sizes, int n_in,
                              void* d_out, int out_size, void* d_ws,
                              size_t ws_size, hipStream_t stream) {
  const void* x   = d_in[0];
  const void* W_b = d_in[1];
  const void* b_b = d_in[2];
  const void* Wk  = d_in[3];
  const void* Wv  = d_in[4];
  const void* Wq  = d_in[5];
  const void* W_m = d_in[6];
  const void* b_m = d_in[7];
  const void* W_f = d_in[8];
  const void* b_f = d_in[9];
  const void* W1  = d_in[10];
  const void* b1  = d_in[11];
  const void* g1  = d_in[12];
  const void* be1 = d_in[13];
  const void* W2  = d_in[14];
  const void* b2  = d_in[15];

  float* w = (float*)d_ws;
  float* kbuf   = w;                    // 262144
  float* vbuf   = w + 262144;           // 262144
  float* scal4  = w + 524288;           // 8192  (theta,eta,alpha,0) per (b,t)
  float* q_last = w + 532480;           // 1024
  float* f_last = w + 533504;           // 1024
  float* m_last = w + 534528;           // 1024
  int*   flag   = (int*)(w + 535552);

  k0_detect<<<1, 256, 0, stream>>>(x, flag);
  k1_kern<<<BB * TT, 128, 0, stream>>>(x, W_b, b_b, Wk, Wv, Wq, W_m, b_m,
                                       flag, kbuf, vbuf, scal4, q_last,
                                       f_last);
  k2_scan<<<64, 256, 0, stream>>>(kbuf, vbuf, scal4, q_last, m_last);
  k3_kern<<<BB, 256, 0, stream>>>(f_last, m_last, W_f, b_f, W1, b1, g1, be1,
                                  W2, b2, flag, d_out);
}

// Round 3
// 223.820 us; speedup vs baseline: 1.3938x; 1.3938x over previous
//
#include <hip/hip_runtime.h>
#include <hip/hip_bf16.h>

#define BB 8
#define TT 256
#define DIN 64
#define DD 128

__device__ __forceinline__ float gelu_tanh(float x) {
  float x3 = x * x * x;
  return 0.5f * x * (1.0f + tanhf(0.7978845608028654f * (x + 0.044715f * x3)));
}
__device__ __forceinline__ float sigmoidf(float x) {
  return 1.0f / (1.0f + __expf(-x));
}

template <typename T> __device__ __forceinline__ float getv(const void* p, int i);
template <> __device__ __forceinline__ float getv<float>(const void* p, int i) {
  return ((const float*)p)[i];
}
template <> __device__ __forceinline__ float getv<__hip_bfloat16>(const void* p, int i) {
  return __bfloat162float(((const __hip_bfloat16*)p)[i]);
}

// DPP-based add from a statically-controlled source lane. All-VALU
// (~8 cyc/stage) instead of ds_swizzle's DS-pipe (~120 cyc/stage).
// Harness-validated correct in round 1 (absmax unchanged vs shfl version).
template <int CTRL>
__device__ __forceinline__ float dpp_add(float x) {
  int s = __builtin_amdgcn_update_dpp(0, __float_as_int(x), CTRL, 0xF, 0xF, true);
  return x + __int_as_float(s);
}

// Sum across a 16-lane row (chains are 16 consecutive lanes, row-aligned).
__device__ __forceinline__ float rowsum16(float p) {
  p = dpp_add<0xB1>(p);   // quad_perm [1,0,3,2]  (xor 1)
  p = dpp_add<0x4E>(p);   // quad_perm [2,3,0,1]  (xor 2)
  p = dpp_add<0x124>(p);  // row_ror:4
  p = dpp_add<0x128>(p);  // row_ror:8
  return p;
}

// ---------------------------------------------------------------------------
// k0: dtype detector. Interprets x's first 2048 uint16 as bf16; real bf16
// N(0,1) data decodes ~99.9% into [1e-4,100]; an fp32 bitstream only ~55%.
// flag=1 -> bf16, flag=0 -> fp32.
// ---------------------------------------------------------------------------
__global__ void k0_detect(const void* x, int* flag) {
  __shared__ int cnt;
  if (threadIdx.x == 0) cnt = 0;
  __syncthreads();
  const unsigned short* u = (const unsigned short*)x;
  int good = 0;
  for (int idx = threadIdx.x; idx < 2048; idx += 256) {
    unsigned int bits = ((unsigned int)u[idx]) << 16;
    float f = __uint_as_float(bits);
    float a = fabsf(f);
    if (a == 0.0f || (a > 1e-4f && a < 100.0f)) good++;
  }
  atomicAdd(&cnt, good);
  __syncthreads();
  if (threadIdx.x == 0) *flag = (cnt >= 1536) ? 1 : 0;
}

// ---------------------------------------------------------------------------
// k1: per (b,t) row: f = gelu(x@W_b+b_b); k=f@Wk; v=f@Wv; meta scalars.
// q and f kept only for t=T-1 (only fused[:, -1, :] feeds the head).
// Grid 2048 blocks x 128 threads.
// ---------------------------------------------------------------------------
template <typename T>
__device__ void k1_body(const void* x, const void* W_b, const void* b_b,
                        const void* Wk, const void* Wv, const void* Wq,
                        const void* W_m, const void* b_m,
                        float* kout, float* vout, float* scal4,
                        float* q_last, float* f_last) {
  const int row = blockIdx.x;          // 0..2047
  const int b = row >> 8, t = row & 255;
  const int tid = threadIdx.x;         // 0..127
  __shared__ float xs[DIN];
  __shared__ float fs[DD];
  if (tid < DIN) xs[tid] = getv<T>(x, row * DIN + tid);
  __syncthreads();

  float acc = getv<T>(b_b, tid);
#pragma unroll 8
  for (int d = 0; d < DIN; ++d) acc += xs[d] * getv<T>(W_b, d * DD + tid);
  float f = gelu_tanh(acc);
  fs[tid] = f;
  __syncthreads();

  float ak = 0.0f, av = 0.0f;
#pragma unroll 8
  for (int c = 0; c < DD; ++c) {
    float fc = fs[c];
    ak += fc * getv<T>(Wk, c * DD + tid);
    av += fc * getv<T>(Wv, c * DD + tid);
  }
  kout[row * DD + tid] = ak;
  vout[row * DD + tid] = av;

  if (t == TT - 1) {
    float aq = 0.0f;
#pragma unroll 8
    for (int c = 0; c < DD; ++c) aq += fs[c] * getv<T>(Wq, c * DD + tid);
    q_last[b * DD + tid] = aq;
    f_last[b * DD + tid] = f;
  }
  if (tid < 4) {
    float val = 0.0f;
    if (tid < 3) {
      float a = getv<T>(b_m, tid);
      for (int c = 0; c < DD; ++c) a += fs[c] * getv<T>(W_m, c * 3 + tid);
      float s = sigmoidf(a);
      val = (tid == 0) ? 0.01f * s : ((tid == 1) ? s : 0.1f * s);
    }
    scal4[row * 4 + tid] = val;  // (theta, eta, alpha, 0)
  }
}

__global__ __launch_bounds__(128) void k1_kern(
    const void* x, const void* W_b, const void* b_b, const void* Wk,
    const void* Wv, const void* Wq, const void* W_m, const void* b_m,
    const int* flag, float* kout, float* vout, float* scal4, float* q_last,
    float* f_last) {
  if (*flag)
    k1_body<__hip_bfloat16>(x, W_b, b_b, Wk, Wv, Wq, W_m, b_m, kout, vout,
                            scal4, q_last, f_last);
  else
    k1_body<float>(x, W_b, b_b, Wk, Wv, Wq, W_m, b_m, kout, vout, scal4,
                   f_last ? q_last : q_last, f_last);
}

// ---------------------------------------------------------------------------
// k2: the scan. 1024 independent row-chains (b,i); one chain = 16 lanes,
// 8 fp32 M + 8 fp32 S elems per lane in registers.
//
// vs round 0 (89.6us): ONLY two deltas, both individually characterized:
//  - reduction via DPP (quad_perm/row_ror), all-VALU. Round-1 counters
//    showed its busy-seconds cost is small and correctness is validated;
//    removes the ~450cyc/step serial ds_swizzle chain.
//  - packing: 16 blocks x 1024 threads (same 256 waves) -> 4 independent
//    chains per SIMD, so vmcnt stalls of one wave hide under issue of the
//    others. k2 has no barriers; block size is purely a packing lever.
// Memory structure (1-ahead prefetch, unroll 2, b-major mapping) is the
// round-0 known-good one; round 1's 4-deep refill + same-b-same-XCD
// mapping caused pure memory-stall regression and is reverted.
// ---------------------------------------------------------------------------
__global__ __launch_bounds__(1024) void k2_scan(
    const float* __restrict__ kbuf, const float* __restrict__ vbuf,
    const float* __restrict__ scal, const float* __restrict__ q_last,
    float* __restrict__ m_last) {
  const int tid = threadIdx.x;
  const int g = tid & 15;
  const int chain = blockIdx.x * 64 + (tid >> 4);  // 0..1023
  const int b = chain >> 7;
  const int i = chain & 127;

  const float4* kp = (const float4*)(kbuf + (size_t)b * TT * DD) + (g << 1);
  const float* vp = vbuf + (size_t)b * TT * DD + i;
  const float4* sp = (const float4*)(scal) + b * TT;

  float4 Ma = {0, 0, 0, 0}, Mb = {0, 0, 0, 0};
  float4 Sa = {0, 0, 0, 0}, Sb = {0, 0, 0, 0};
  float4 ka = kp[0], kb = kp[1];
  float vv = vp[0];
  float4 sc = sp[0];

#pragma unroll 2
  for (int t = 0; t < TT; ++t) {
    const int t2 = (t + 1) & (TT - 1);  // wraps to 0 at the end (valid addr)
    float4 nka = kp[t2 * 32];
    float4 nkb = kp[t2 * 32 + 1];
    float nv = vp[t2 * 128];
    float4 nsc = sp[t2];

    float p = (Ma.x * ka.x + Ma.y * ka.y) + (Ma.z * ka.z + Ma.w * ka.w) +
              (Mb.x * kb.x + Mb.y * kb.y) + (Mb.z * kb.z + Mb.w * kb.w);
    p = rowsum16(p);

    const float err = p - vv;
    const float c = sc.x * err;   // theta * err
    const float et = sc.y;        // eta
    const float am = 1.0f - sc.z; // 1 - alpha

    Sa.x = et * Sa.x - c * ka.x;  Ma.x = am * Ma.x + Sa.x;
    Sa.y = et * Sa.y - c * ka.y;  Ma.y = am * Ma.y + Sa.y;
    Sa.z = et * Sa.z - c * ka.z;  Ma.z = am * Ma.z + Sa.z;
    Sa.w = et * Sa.w - c * ka.w;  Ma.w = am * Ma.w + Sa.w;
    Sb.x = et * Sb.x - c * kb.x;  Mb.x = am * Mb.x + Sb.x;
    Sb.y = et * Sb.y - c * kb.y;  Mb.y = am * Mb.y + Sb.y;
    Sb.z = et * Sb.z - c * kb.z;  Mb.z = am * Mb.z + Sb.z;
    Sb.w = et * Sb.w - c * kb.w;  Mb.w = am * Mb.w + Sb.w;

    ka = nka; kb = nkb; vv = nv; sc = nsc;
  }

  const float4* qp = (const float4*)(q_last + b * DD) + (g << 1);
  float4 qa = qp[0], qb = qp[1];
  float p = (Ma.x * qa.x + Ma.y * qa.y) + (Ma.z * qa.z + Ma.w * qa.w) +
            (Mb.x * qb.x + Mb.y * qb.y) + (Mb.z * qb.z + Mb.w * qb.w);
  p = rowsum16(p);
  if (g == 0) m_last[b * DD + i] = p;
}

// ---------------------------------------------------------------------------
// k3: head. gate -> fused -> W1+LN+gelu -> W2. 8 blocks x 256 threads.
// ---------------------------------------------------------------------------
template <typename T>
__device__ void k3_body(const float* f_last, const float* m_last,
                        const void* W_f, const void* b_f, const void* W1,
                        const void* b1, const void* g1, const void* be1,
                        const void* W2, const void* b2, void* out) {
  const int b = blockIdx.x, tid = threadIdx.x;
  __shared__ float fm[2 * DD];
  __shared__ float fused[DD];
  __shared__ float tmp[DD];
  __shared__ float h[DD];
  __shared__ float smu, srs;

  fm[tid] = (tid < DD) ? f_last[b * DD + tid] : m_last[b * DD + tid - DD];
  __syncthreads();

  if (tid < DD) {
    float a = getv<T>(b_f, tid);
#pragma unroll 8
    for (int c = 0; c < 2 * DD; ++c) a += fm[c] * getv<T>(W_f, c * DD + tid);
    float gte = sigmoidf(a);
    fused[tid] = fm[tid] * gte + fm[DD + tid] * (1.0f - gte);
  }
  __syncthreads();

  if (tid < DD) {
    float a = getv<T>(b1, tid);
#pragma unroll 8
    for (int c = 0; c < DD; ++c) a += fused[c] * getv<T>(W1, c * DD + tid);
    tmp[tid] = a;
  }
  __syncthreads();

  if (tid == 0) {
    float s = 0.0f;
    for (int c = 0; c < DD; ++c) s += tmp[c];
    float mu = s / (float)DD;
    float s2 = 0.0f;
    for (int c = 0; c < DD; ++c) {
      float d = tmp[c] - mu;
      s2 += d * d;
    }
    smu = mu;
    srs = rsqrtf(s2 / (float)DD + 1e-5f);
  }
  __syncthreads();

  if (tid < DD)
    h[tid] = gelu_tanh((tmp[tid] - smu) * srs * getv<T>(g1, tid) +
                       getv<T>(be1, tid));
  __syncthreads();

  for (int j = tid; j < 672; j += 256) {
    float a = getv<T>(b2, j);
#pragma unroll 8
    for (int c = 0; c < DD; ++c) a += h[c] * getv<T>(W2, c * 672 + j);
    if (sizeof(T) == 2)
      ((__hip_bfloat16*)out)[b * 672 + j] = __float2bfloat16(a);
    else
      ((float*)out)[b * 672 + j] = a;
  }
}

__global__ __launch_bounds__(256) void k3_kern(
    const float* f_last, const float* m_last, const void* W_f,
    const void* b_f, const void* W1, const void* b1, const void* g1,
    const void* be1, const void* W2, const void* b2, const int* flag,
    void* out) {
  if (*flag)
    k3_body<__hip_bfloat16>(f_last, m_last, W_f, b_f, W1, b1, g1, be1, W2, b2,
                            out);
  else
    k3_body<float>(f_last, m_last, W_f, b_f, W1, b1, g1, be1, W2, b2, out);
}

// ---------------------------------------------------------------------------
extern "C" void kernel_launch(void* const* d_in, const int* in_sizes, int n_in,
                              void* d_out, int out_size, void* d_ws,
                              size_t ws_size, hipStream_t stream) {
  const void* x   = d_in[0];
  const void* W_b = d_in[1];
  const void* b_b = d_in[2];
  const void* Wk  = d_in[3];
  const void* Wv  = d_in[4];
  const void* Wq  = d_in[5];
  const void* W_m = d_in[6];
  const void* b_m = d_in[7];
  const void* W_f = d_in[8];
  const void* b_f = d_in[9];
  const void* W1  = d_in[10];
  const void* b1  = d_in[11];
  const void* g1  = d_in[12];
  const void* be1 = d_in[13];
  const void* W2  = d_in[14];
  const void* b2  = d_in[15];

  float* w = (float*)d_ws;
  float* kbuf   = w;                    // 262144
  float* vbuf   = w + 262144;           // 262144
  float* scal4  = w + 524288;           // 8192  (theta,eta,alpha,0) per (b,t)
  float* q_last = w + 532480;           // 1024
  float* f_last = w + 533504;           // 1024
  float* m_last = w + 534528;           // 1024
  int*   flag   = (int*)(w + 535552);

  k0_detect<<<1, 256, 0, stream>>>(x, flag);
  k1_kern<<<BB * TT, 128, 0, stream>>>(x, W_b, b_b, Wk, Wv, Wq, W_m, b_m,
                                       flag, kbuf, vbuf, scal4, q_last,
                                       f_last);
  k2_scan<<<16, 1024, 0, stream>>>(kbuf, vbuf, scal4, q_last, m_last);
  k3_kern<<<BB, 256, 0, stream>>>(f_last, m_last, W_f, b_f, W1, b1, g1, be1,
                                  W2, b2, flag, d_out);
}

// Round 4
// 194.506 us; speedup vs baseline: 1.6038x; 1.1507x over previous
//
#include <hip/hip_runtime.h>
#include <hip/hip_bf16.h>

#define BB 8
#define TT 256
#define DIN 64
#define DD 128

__device__ __forceinline__ float gelu_tanh(float x) {
  float x3 = x * x * x;
  return 0.5f * x * (1.0f + tanhf(0.7978845608028654f * (x + 0.044715f * x3)));
}
__device__ __forceinline__ float sigmoidf(float x) {
  return 1.0f / (1.0f + __expf(-x));
}

template <typename T> __device__ __forceinline__ float getv(const void* p, int i);
template <> __device__ __forceinline__ float getv<float>(const void* p, int i) {
  return ((const float*)p)[i];
}
template <> __device__ __forceinline__ float getv<__hip_bfloat16>(const void* p, int i) {
  return __bfloat162float(((const __hip_bfloat16*)p)[i]);
}

// DPP-based add from a statically-controlled source lane. All-VALU
// (~8 cyc/stage) instead of ds_swizzle's DS-pipe (~120 cyc/stage).
// Harness-validated correct in rounds 1/3 (absmax identical to shfl version).
template <int CTRL>
__device__ __forceinline__ float dpp_add(float x) {
  int s = __builtin_amdgcn_update_dpp(0, __float_as_int(x), CTRL, 0xF, 0xF, true);
  return x + __int_as_float(s);
}

// Sum across a 16-lane row (chains are 16 consecutive lanes, row-aligned).
__device__ __forceinline__ float rowsum16(float p) {
  p = dpp_add<0xB1>(p);   // quad_perm [1,0,3,2]  (xor 1)
  p = dpp_add<0x4E>(p);   // quad_perm [2,3,0,1]  (xor 2)
  p = dpp_add<0x124>(p);  // row_ror:4
  p = dpp_add<0x128>(p);  // row_ror:8
  return p;
}

// ---------------------------------------------------------------------------
// k0: dtype detector. Interprets x's first 2048 uint16 as bf16; real bf16
// N(0,1) data decodes ~99.9% into [1e-4,100]; an fp32 bitstream only ~55%.
// flag=1 -> bf16, flag=0 -> fp32.
// ---------------------------------------------------------------------------
__global__ void k0_detect(const void* x, int* flag) {
  __shared__ int cnt;
  if (threadIdx.x == 0) cnt = 0;
  __syncthreads();
  const unsigned short* u = (const unsigned short*)x;
  int good = 0;
  for (int idx = threadIdx.x; idx < 2048; idx += 256) {
    unsigned int bits = ((unsigned int)u[idx]) << 16;
    float f = __uint_as_float(bits);
    float a = fabsf(f);
    if (a == 0.0f || (a > 1e-4f && a < 100.0f)) good++;
  }
  atomicAdd(&cnt, good);
  __syncthreads();
  if (threadIdx.x == 0) *flag = (cnt >= 1536) ? 1 : 0;
}

// ---------------------------------------------------------------------------
// k1: per (b,t) row: f = gelu(x@W_b+b_b); k=f@Wk; v=f@Wv; meta scalars.
// q and f kept only for t=T-1 (only fused[:, -1, :] feeds the head).
// Grid 2048 blocks x 128 threads.
// ---------------------------------------------------------------------------
template <typename T>
__device__ void k1_body(const void* x, const void* W_b, const void* b_b,
                        const void* Wk, const void* Wv, const void* Wq,
                        const void* W_m, const void* b_m,
                        float* kout, float* vout, float* scal4,
                        float* q_last, float* f_last) {
  const int row = blockIdx.x;          // 0..2047
  const int b = row >> 8, t = row & 255;
  const int tid = threadIdx.x;         // 0..127
  __shared__ float xs[DIN];
  __shared__ float fs[DD];
  if (tid < DIN) xs[tid] = getv<T>(x, row * DIN + tid);
  __syncthreads();

  float acc = getv<T>(b_b, tid);
#pragma unroll 8
  for (int d = 0; d < DIN; ++d) acc += xs[d] * getv<T>(W_b, d * DD + tid);
  float f = gelu_tanh(acc);
  fs[tid] = f;
  __syncthreads();

  float ak = 0.0f, av = 0.0f;
#pragma unroll 8
  for (int c = 0; c < DD; ++c) {
    float fc = fs[c];
    ak += fc * getv<T>(Wk, c * DD + tid);
    av += fc * getv<T>(Wv, c * DD + tid);
  }
  kout[row * DD + tid] = ak;
  vout[row * DD + tid] = av;

  if (t == TT - 1) {
    float aq = 0.0f;
#pragma unroll 8
    for (int c = 0; c < DD; ++c) aq += fs[c] * getv<T>(Wq, c * DD + tid);
    q_last[b * DD + tid] = aq;
    f_last[b * DD + tid] = f;
  }
  if (tid < 4) {
    float val = 0.0f;
    if (tid < 3) {
      float a = getv<T>(b_m, tid);
      for (int c = 0; c < DD; ++c) a += fs[c] * getv<T>(W_m, c * 3 + tid);
      float s = sigmoidf(a);
      val = (tid == 0) ? 0.01f * s : ((tid == 1) ? s : 0.1f * s);
    }
    scal4[row * 4 + tid] = val;  // (theta, eta, alpha, 0)
  }
}

__global__ __launch_bounds__(128) void k1_kern(
    const void* x, const void* W_b, const void* b_b, const void* Wk,
    const void* Wv, const void* Wq, const void* W_m, const void* b_m,
    const int* flag, float* kout, float* vout, float* scal4, float* q_last,
    float* f_last) {
  if (*flag)
    k1_body<__hip_bfloat16>(x, W_b, b_b, Wk, Wv, Wq, W_m, b_m, kout, vout,
                            scal4, q_last, f_last);
  else
    k1_body<float>(x, W_b, b_b, Wk, Wv, Wq, W_m, b_m, kout, vout, scal4,
                   q_last, f_last);
}

// ---------------------------------------------------------------------------
// k2: the scan. 1024 independent row-chains (b,i); one chain = 16 lanes,
// 8 fp32 M + 8 fp32 S elems per lane in registers.
//
// Geometry history (the lever this round):
//  - r0: 64 blk x 256 thr (64 CUs, 4 wv/CU) + ds_swizzle reduce: 840 cyc/step.
//  - r3: 16 blk x 1024 thr (16 CUs!) + DPP reduce: 782 cyc/step. Whole-chip
//    VALUBusy 5% = ~80% on the 16 ACTIVE CUs -> VALU-issue-bound locally.
//  - r4 (this): 256 blk x 64 thr -> 1 wave per CU across all 256 CUs.
//    Per-CU VALU pressure /16; per-step becomes chain (~80cyc) + exposed L2
//    latency under 1-ahead prefetch. DPP reduce kept (validated r1/r3).
// All 4 chains of a wave share b -> kp base is wave-uniform (SGPR).
// ---------------------------------------------------------------------------
__global__ __launch_bounds__(64) void k2_scan(
    const float* __restrict__ kbuf, const float* __restrict__ vbuf,
    const float* __restrict__ scal, const float* __restrict__ q_last,
    float* __restrict__ m_last) {
  const int tid = threadIdx.x;
  const int g = tid & 15;
  const int chain = blockIdx.x * 4 + (tid >> 4);  // 0..1023
  const int b = chain >> 7;
  const int i = chain & 127;

  const float4* kp = (const float4*)(kbuf + (size_t)b * TT * DD) + (g << 1);
  const float* vp = vbuf + (size_t)b * TT * DD + i;
  const float4* sp = (const float4*)(scal) + b * TT;

  float4 Ma = {0, 0, 0, 0}, Mb = {0, 0, 0, 0};
  float4 Sa = {0, 0, 0, 0}, Sb = {0, 0, 0, 0};
  float4 ka = kp[0], kb = kp[1];
  float vv = vp[0];
  float4 sc = sp[0];

#pragma unroll 2
  for (int t = 0; t < TT; ++t) {
    const int t2 = (t + 1) & (TT - 1);  // wraps to 0 at the end (valid addr)
    float4 nka = kp[t2 * 32];
    float4 nkb = kp[t2 * 32 + 1];
    float nv = vp[t2 * 128];
    float4 nsc = sp[t2];

    float p = (Ma.x * ka.x + Ma.y * ka.y) + (Ma.z * ka.z + Ma.w * ka.w) +
              (Mb.x * kb.x + Mb.y * kb.y) + (Mb.z * kb.z + Mb.w * kb.w);
    p = rowsum16(p);

    const float err = p - vv;
    const float c = sc.x * err;   // theta * err
    const float et = sc.y;        // eta
    const float am = 1.0f - sc.z; // 1 - alpha

    Sa.x = et * Sa.x - c * ka.x;  Ma.x = am * Ma.x + Sa.x;
    Sa.y = et * Sa.y - c * ka.y;  Ma.y = am * Ma.y + Sa.y;
    Sa.z = et * Sa.z - c * ka.z;  Ma.z = am * Ma.z + Sa.z;
    Sa.w = et * Sa.w - c * ka.w;  Ma.w = am * Ma.w + Sa.w;
    Sb.x = et * Sb.x - c * kb.x;  Mb.x = am * Mb.x + Sb.x;
    Sb.y = et * Sb.y - c * kb.y;  Mb.y = am * Mb.y + Sb.y;
    Sb.z = et * Sb.z - c * kb.z;  Mb.z = am * Mb.z + Sb.z;
    Sb.w = et * Sb.w - c * kb.w;  Mb.w = am * Mb.w + Sb.w;

    ka = nka; kb = nkb; vv = nv; sc = nsc;
  }

  const float4* qp = (const float4*)(q_last + b * DD) + (g << 1);
  float4 qa = qp[0], qb = qp[1];
  float p = (Ma.x * qa.x + Ma.y * qa.y) + (Ma.z * qa.z + Ma.w * qa.w) +
            (Mb.x * qb.x + Mb.y * qb.y) + (Mb.z * qb.z + Mb.w * qb.w);
  p = rowsum16(p);
  if (g == 0) m_last[b * DD + i] = p;
}

// ---------------------------------------------------------------------------
// k3: head. gate -> fused -> W1+LN+gelu -> W2. 8 blocks x 256 threads.
// ---------------------------------------------------------------------------
template <typename T>
__device__ void k3_body(const float* f_last, const float* m_last,
                        const void* W_f, const void* b_f, const void* W1,
                        const void* b1, const void* g1, const void* be1,
                        const void* W2, const void* b2, void* out) {
  const int b = blockIdx.x, tid = threadIdx.x;
  __shared__ float fm[2 * DD];
  __shared__ float fused[DD];
  __shared__ float tmp[DD];
  __shared__ float h[DD];
  __shared__ float smu, srs;

  fm[tid] = (tid < DD) ? f_last[b * DD + tid] : m_last[b * DD + tid - DD];
  __syncthreads();

  if (tid < DD) {
    float a = getv<T>(b_f, tid);
#pragma unroll 8
    for (int c = 0; c < 2 * DD; ++c) a += fm[c] * getv<T>(W_f, c * DD + tid);
    float gte = sigmoidf(a);
    fused[tid] = fm[tid] * gte + fm[DD + tid] * (1.0f - gte);
  }
  __syncthreads();

  if (tid < DD) {
    float a = getv<T>(b1, tid);
#pragma unroll 8
    for (int c = 0; c < DD; ++c) a += fused[c] * getv<T>(W1, c * DD + tid);
    tmp[tid] = a;
  }
  __syncthreads();

  if (tid == 0) {
    float s = 0.0f;
    for (int c = 0; c < DD; ++c) s += tmp[c];
    float mu = s / (float)DD;
    float s2 = 0.0f;
    for (int c = 0; c < DD; ++c) {
      float d = tmp[c] - mu;
      s2 += d * d;
    }
    smu = mu;
    srs = rsqrtf(s2 / (float)DD + 1e-5f);
  }
  __syncthreads();

  if (tid < DD)
    h[tid] = gelu_tanh((tmp[tid] - smu) * srs * getv<T>(g1, tid) +
                       getv<T>(be1, tid));
  __syncthreads();

  for (int j = tid; j < 672; j += 256) {
    float a = getv<T>(b2, j);
#pragma unroll 8
    for (int c = 0; c < DD; ++c) a += h[c] * getv<T>(W2, c * 672 + j);
    if (sizeof(T) == 2)
      ((__hip_bfloat16*)out)[b * 672 + j] = __float2bfloat16(a);
    else
      ((float*)out)[b * 672 + j] = a;
  }
}

__global__ __launch_bounds__(256) void k3_kern(
    const float* f_last, const float* m_last, const void* W_f,
    const void* b_f, const void* W1, const void* b1, const void* g1,
    const void* be1, const void* W2, const void* b2, const int* flag,
    void* out) {
  if (*flag)
    k3_body<__hip_bfloat16>(f_last, m_last, W_f, b_f, W1, b1, g1, be1, W2, b2,
                            out);
  else
    k3_body<float>(f_last, m_last, W_f, b_f, W1, b1, g1, be1, W2, b2, out);
}

// ---------------------------------------------------------------------------
extern "C" void kernel_launch(void* const* d_in, const int* in_sizes, int n_in,
                              void* d_out, int out_size, void* d_ws,
                              size_t ws_size, hipStream_t stream) {
  const void* x   = d_in[0];
  const void* W_b = d_in[1];
  const void* b_b = d_in[2];
  const void* Wk  = d_in[3];
  const void* Wv  = d_in[4];
  const void* Wq  = d_in[5];
  const void* W_m = d_in[6];
  const void* b_m = d_in[7];
  const void* W_f = d_in[8];
  const void* b_f = d_in[9];
  const void* W1  = d_in[10];
  const void* b1  = d_in[11];
  const void* g1  = d_in[12];
  const void* be1 = d_in[13];
  const void* W2  = d_in[14];
  const void* b2  = d_in[15];

  float* w = (float*)d_ws;
  float* kbuf   = w;                    // 262144
  float* vbuf   = w + 262144;           // 262144
  float* scal4  = w + 524288;           // 8192  (theta,eta,alpha,0) per (b,t)
  float* q_last = w + 532480;           // 1024
  float* f_last = w + 533504;           // 1024
  float* m_last = w + 534528;           // 1024
  int*   flag   = (int*)(w + 535552);

  k0_detect<<<1, 256, 0, stream>>>(x, flag);
  k1_kern<<<BB * TT, 128, 0, stream>>>(x, W_b, b_b, Wk, Wv, Wq, W_m, b_m,
                                       flag, kbuf, vbuf, scal4, q_last,
                                       f_last);
  k2_scan<<<256, 64, 0, stream>>>(kbuf, vbuf, scal4, q_last, m_last);
  k3_kern<<<BB, 256, 0, stream>>>(f_last, m_last, W_f, b_f, W1, b1, g1, be1,
                                  W2, b2, flag, d_out);
}